// Round 5
// baseline (68.857 us; speedup 1.0000x reference)
//
#include <hip/hip_runtime.h>

// Problem constants (fixed in reference source)
#define NGRAPH 2048
#define TURNS  6
#define NPT    48
#define NHID   128
#define NC4    (NHID / 4)       // 32 float4 columns per node row
#define PAIR_F4 (NPT * NC4)     // 1536 f32x4 per (graph,turn) pair
#define BN_EPS 1e-5f
#define NPAIR  (NGRAPH * TURNS) // 12288
#define ABLK   1536             // 6 blocks/CU * 256 CU, all co-resident
#define AWAVES (ABLK * 4)       // 6144 waves -> exactly 2 pairs per wave

typedef float f32x4 __attribute__((ext_vector_type(4)));

__device__ __forceinline__ f32x4 f4max(f32x4 a, f32x4 b) {
    f32x4 r;
    r.x = fmaxf(a.x, b.x); r.y = fmaxf(a.y, b.y);
    r.z = fmaxf(a.z, b.z); r.w = fmaxf(a.w, b.w);
    return r;
}
__device__ __forceinline__ f32x4 f4min(f32x4 a, f32x4 b) {
    f32x4 r;
    r.x = fminf(a.x, b.x); r.y = fminf(a.y, b.y);
    r.z = fminf(a.z, b.z); r.w = fminf(a.w, b.w);
    return r;
}
__device__ __forceinline__ f32x4 f4shflxor32(f32x4 a) {
    f32x4 r;
    r.x = __shfl_xor(a.x, 32, 64);
    r.y = __shfl_xor(a.y, 32, 64);
    r.z = __shfl_xor(a.z, 32, 64);
    r.w = __shfl_xor(a.w, 32, 64);
    return r;
}

// ---------------- Kernel A: uniform streaming segment reduce -----------------
// 1536 blocks x 256 thr (4 waves) = 6144 waves; exactly 6 blocks/CU resident,
// zero tail, zero barriers, zero divergence. Wave W reduces pairs 2W (even
// turn -> MAX) and 2W+1 (odd turn -> MIN); each pair = 24 contiguous 1 KB
// chunks. Results (32 f32x4 per pair) -> ws.
__global__ __launch_bounds__(256, 6) void ggru_phase1(
    const float* __restrict__ hp, float* __restrict__ ws)
{
    const int tid  = threadIdx.x;
    const int lane = tid & 63;
    const int wv   = (blockIdx.x << 2) | (tid >> 6);   // 0..6143
    const int p0   = wv << 1;                          // even pair id

    const f32x4* baseA = reinterpret_cast<const f32x4*>(hp)
                       + (size_t)p0 * PAIR_F4 + lane;
    const f32x4* baseB = baseA + PAIR_F4;

    // pair A: MAX over 48 rows (24 chunks, lanes = 2 rows/chunk)
    f32x4 a0 = baseA[0 * 64], a1 = baseA[1 * 64],
          a2 = baseA[2 * 64], a3 = baseA[3 * 64];
    #pragma unroll
    for (int c = 4; c < 24; c += 4) {
        a0 = f4max(a0, baseA[(c + 0) * 64]);
        a1 = f4max(a1, baseA[(c + 1) * 64]);
        a2 = f4max(a2, baseA[(c + 2) * 64]);
        a3 = f4max(a3, baseA[(c + 3) * 64]);
    }
    a0 = f4max(f4max(a0, a1), f4max(a2, a3));
    a0 = f4max(a0, f4shflxor32(a0));

    // pair B: MIN over 48 rows
    f32x4 b0 = baseB[0 * 64], b1v = baseB[1 * 64],
          b2 = baseB[2 * 64], b3 = baseB[3 * 64];
    #pragma unroll
    for (int c = 4; c < 24; c += 4) {
        b0  = f4min(b0,  baseB[(c + 0) * 64]);
        b1v = f4min(b1v, baseB[(c + 1) * 64]);
        b2  = f4min(b2,  baseB[(c + 2) * 64]);
        b3  = f4min(b3,  baseB[(c + 3) * 64]);
    }
    b0 = f4min(f4min(b0, b1v), f4min(b2, b3));
    b0 = f4min(b0, f4shflxor32(b0));

    f32x4* wsv = reinterpret_cast<f32x4*>(ws);
    if (lane < 32) {
        wsv[(size_t)p0 * 32 + lane] = a0;
        wsv[(size_t)(p0 + 1) * 32 + lane] = b0;
    }
}

// ---------------- Kernel B: combine + MLP head -------------------------------
// 512 blocks x 256 thr; one wave per graph.
__global__ __launch_bounds__(256) void ggru_phase2(
    const float* __restrict__ ws,
    const float* __restrict__ W1, const float* __restrict__ b1,
    const float* __restrict__ W4, const float* __restrict__ b4,
    const float* __restrict__ bn1_g, const float* __restrict__ bn1_b,
    const float* __restrict__ bn2_g, const float* __restrict__ bn2_b,
    float* __restrict__ out)
{
    __shared__ float xbn[4][2 * NHID];

    const int tid  = threadIdx.x;
    const int wv   = tid >> 6;          // wave in block
    const int lane = tid & 63;
    const int g    = (blockIdx.x << 2) | wv;
    const int half = lane >> 5;         // 0: x1 (max turns), 1: x2 (min turns)
    const int c    = lane & 31;

    const float bn1s = bn1_g[0] / sqrtf(1.0f + BN_EPS);
    const float bn1t = bn1_b[0];
    const float bn2s = bn2_g[0] / sqrtf(1.0f + BN_EPS);
    const float bn2t = bn2_b[0];

    // combine 3 per-turn results (turns half, half+2, half+4)
    const f32x4* wsv = reinterpret_cast<const f32x4*>(ws)
                     + (size_t)(g * TURNS + half) * 32 + c;
    f32x4 s = wsv[0] + wsv[2 * 32] + wsv[4 * 32];
    s = s * bn1s;
    s.x += bn1t; s.y += bn1t; s.z += bn1t; s.w += bn1t;
    reinterpret_cast<f32x4*>(xbn[wv])[lane] = s;   // f4 slot = half*32+c = lane
    __syncthreads();

    // y[h] = relu(dot(W1[h,:], xbn) + b1[h]); h = lane
    float acc = b1[lane];
    const f32x4* wrow = reinterpret_cast<const f32x4*>(W1 + lane * (2 * NHID));
    const f32x4* xv   = reinterpret_cast<const f32x4*>(xbn[wv]);
    #pragma unroll 8
    for (int k = 0; k < (2 * NHID) / 4; ++k) {
        const f32x4 w = wrow[k];
        const f32x4 x = xv[k];          // LDS broadcast
        acc += w.x * x.x + w.y * x.y + w.z * x.z + w.w * x.w;
    }
    float y = fmaxf(acc, 0.0f);
    y = y * bn2s + bn2t;

    float p = y * W4[lane];
    #pragma unroll
    for (int off = 32; off > 0; off >>= 1)
        p += __shfl_down(p, off, 64);
    if (lane == 0)
        out[g] = p + b4[0];
}

extern "C" void kernel_launch(void* const* d_in, const int* in_sizes, int n_in,
                              void* d_out, int out_size, void* d_ws, size_t ws_size,
                              hipStream_t stream) {
    (void)in_sizes; (void)n_in; (void)ws_size; (void)out_size;
    const float* hp    = (const float*)d_in[0];
    // d_in[1] = graph_ids, d_in[2] = turn_ids: layout is deterministic
    // (seg = idx/48, contiguous), so the index arrays are not needed.
    const float* W1    = (const float*)d_in[3];
    const float* b1    = (const float*)d_in[4];
    const float* W4    = (const float*)d_in[5];
    const float* b4    = (const float*)d_in[6];
    const float* bn1_g = (const float*)d_in[7];
    const float* bn1_b = (const float*)d_in[8];
    const float* bn2_g = (const float*)d_in[9];
    const float* bn2_b = (const float*)d_in[10];
    float* out = (float*)d_out;
    float* ws  = (float*)d_ws;   // 12288 pairs * 128 f32 = 6.29 MB, fully
                                 // rewritten by phase1 every call.

    hipLaunchKernelGGL(ggru_phase1, dim3(ABLK), dim3(256), 0, stream, hp, ws);
    hipLaunchKernelGGL(ggru_phase2, dim3(NGRAPH / 4), dim3(256), 0, stream,
                       ws, W1, b1, W4, b4, bn1_g, bn1_b, bn2_g, bn2_b, out);
}

// Round 6
// 56.200 us; speedup vs baseline: 1.2252x; 1.2252x over previous
//
#include <hip/hip_runtime.h>

// Problem constants (fixed in reference source)
#define NGRAPH 2048
#define TURNS  6
#define NPT    48
#define NHID   128
#define NC4    (NHID / 4)     // 32 float4 columns per node row
#define BN_EPS 1e-5f

typedef float f32x4 __attribute__((ext_vector_type(4)));

__device__ __forceinline__ f32x4 f4max(f32x4 a, f32x4 b) {
    f32x4 r;
    r.x = fmaxf(a.x, b.x); r.y = fmaxf(a.y, b.y);
    r.z = fmaxf(a.z, b.z); r.w = fmaxf(a.w, b.w);
    return r;
}
__device__ __forceinline__ f32x4 f4min(f32x4 a, f32x4 b) {
    f32x4 r;
    r.x = fminf(a.x, b.x); r.y = fminf(a.y, b.y);
    r.z = fminf(a.z, b.z); r.w = fminf(a.w, b.w);
    return r;
}
__device__ __forceinline__ f32x4 f4shflxor32(f32x4 a) {
    f32x4 r;
    r.x = __shfl_xor(a.x, 32, 64);
    r.y = __shfl_xor(a.y, 32, 64);
    r.z = __shfl_xor(a.z, 32, 64);
    r.w = __shfl_xor(a.w, 32, 64);
    return r;
}
__device__ __forceinline__ f32x4 ntload(const f32x4* p) {
    return __builtin_nontemporal_load(p);
}

// R2 structure (best known: 56.4 us) + non-temporal hp loads (single change).
// One block per graph, 384 threads = 6 waves, one wave per turn.
// Phase 1: wave w streams turn w's 48x128 f32 block as 24 contiguous 1 KB
//          chunks (2 rows each), 4 independent acc chains, shfl_xor(32) merge.
// Phase 2: combine even-turn maxes (x1) / odd-turn mins (x2), BN1 -> xbn.
// Phase 3: 64 threads x one W1-row dot, ReLU, BN2, 64-lane shuffle dot with
//          W4, +b4 -> out[g].
__global__ __launch_bounds__(384) void ggru_readout_mlp(
    const float* __restrict__ hp,
    const float* __restrict__ W1, const float* __restrict__ b1,
    const float* __restrict__ W4, const float* __restrict__ b4,
    const float* __restrict__ bn1_g, const float* __restrict__ bn1_b,
    const float* __restrict__ bn2_g, const float* __restrict__ bn2_b,
    float* __restrict__ out)
{
    __shared__ f32x4 segres[TURNS][NC4];   // per-turn reduced row (cols 0..31)
    __shared__ float xbn[2 * NHID];        // BN1-applied concat [x1 | x2]

    const int g    = blockIdx.x;
    const int tid  = threadIdx.x;
    const int lane = tid & 63;
    const int turn = tid >> 6;             // wave id 0..5

    // (g, turn) block: 48 rows x 32 f4 = 1536 f4, contiguous. 24 chunks of
    // 64 f4 (1 KB); lane covers f4 #lane of each chunk.
    const f32x4* base = reinterpret_cast<const f32x4*>(hp)
                      + (size_t)(g * TURNS + turn) * (NPT * NC4) + lane;

    f32x4 a0 = ntload(&base[0 * 64]);
    f32x4 a1 = ntload(&base[1 * 64]);
    f32x4 a2 = ntload(&base[2 * 64]);
    f32x4 a3 = ntload(&base[3 * 64]);
    if ((turn & 1) == 0) {
        #pragma unroll
        for (int c = 4; c < 24; c += 4) {
            a0 = f4max(a0, ntload(&base[(c + 0) * 64]));
            a1 = f4max(a1, ntload(&base[(c + 1) * 64]));
            a2 = f4max(a2, ntload(&base[(c + 2) * 64]));
            a3 = f4max(a3, ntload(&base[(c + 3) * 64]));
        }
        a0 = f4max(f4max(a0, a1), f4max(a2, a3));
        a0 = f4max(a0, f4shflxor32(a0));   // merge even/odd row halves
    } else {
        #pragma unroll
        for (int c = 4; c < 24; c += 4) {
            a0 = f4min(a0, ntload(&base[(c + 0) * 64]));
            a1 = f4min(a1, ntload(&base[(c + 1) * 64]));
            a2 = f4min(a2, ntload(&base[(c + 2) * 64]));
            a3 = f4min(a3, ntload(&base[(c + 3) * 64]));
        }
        a0 = f4min(f4min(a0, a1), f4min(a2, a3));
        a0 = f4min(a0, f4shflxor32(a0));
    }
    if (lane < 32)
        segres[turn][lane] = a0;
    __syncthreads();

    if (tid < 64) {
        const int c = tid & 31;
        f32x4 s;
        if (tid < 32) {
            // x1: sum of maxes over even turns 0,2,4  -> features [0,128)
            s = segres[0][c] + segres[2][c] + segres[4][c];
        } else {
            // x2: sum of mins over odd turns 1,3,5    -> features [128,256)
            s = segres[1][c] + segres[3][c] + segres[5][c];
        }
        // BN1 (eval, single channel): x * (gamma/sqrt(1+eps)) + beta
        const float s1 = bn1_g[0] / sqrtf(1.0f + BN_EPS);
        const float t1 = bn1_b[0];
        s = s * s1;
        s.x += t1; s.y += t1; s.z += t1; s.w += t1;
        reinterpret_cast<f32x4*>(xbn)[tid] = s;
    }
    __syncthreads();

    if (tid < 64) {
        // y[h] = relu(dot(W1[h,:], xbn) + b1[h])
        float acc2 = b1[tid];
        const f32x4* w  = reinterpret_cast<const f32x4*>(W1 + tid * (2 * NHID));
        const f32x4* xv = reinterpret_cast<const f32x4*>(xbn);
        #pragma unroll 8
        for (int k = 0; k < (2 * NHID) / 4; ++k) {
            const f32x4 wv = w[k];
            const f32x4 x  = xv[k];   // LDS broadcast (all lanes same addr)
            acc2 += wv.x * x.x + wv.y * x.y + wv.z * x.z + wv.w * x.w;
        }
        float y = fmaxf(acc2, 0.0f);
        const float s2 = bn2_g[0] / sqrtf(1.0f + BN_EPS);
        y = y * s2 + bn2_b[0];

        float p = y * W4[tid];
        #pragma unroll
        for (int off = 32; off > 0; off >>= 1)
            p += __shfl_down(p, off, 64);
        if (tid == 0)
            out[g] = p + b4[0];
    }
}

extern "C" void kernel_launch(void* const* d_in, const int* in_sizes, int n_in,
                              void* d_out, int out_size, void* d_ws, size_t ws_size,
                              hipStream_t stream) {
    (void)in_sizes; (void)n_in; (void)d_ws; (void)ws_size; (void)out_size;
    const float* hp    = (const float*)d_in[0];
    // d_in[1] = graph_ids, d_in[2] = turn_ids: layout is deterministic
    // (seg = idx/48, contiguous), so the index arrays are not needed.
    const float* W1    = (const float*)d_in[3];
    const float* b1    = (const float*)d_in[4];
    const float* W4    = (const float*)d_in[5];
    const float* b4    = (const float*)d_in[6];
    const float* bn1_g = (const float*)d_in[7];
    const float* bn1_b = (const float*)d_in[8];
    const float* bn2_g = (const float*)d_in[9];
    const float* bn2_b = (const float*)d_in[10];
    float* out = (float*)d_out;

    hipLaunchKernelGGL(ggru_readout_mlp, dim3(NGRAPH), dim3(384), 0, stream,
                       hp, W1, b1, W4, b4, bn1_g, bn1_b, bn2_g, bn2_b, out);
}